// Round 5
// baseline (342.515 us; speedup 1.0000x reference)
//
#include <hip/hip_runtime.h>
#include <stdint.h>

typedef unsigned short u16;
typedef __bf16 bf16x8 __attribute__((ext_vector_type(8)));
typedef float f32x4 __attribute__((ext_vector_type(4)));

#define N_NODES 50000
#define N_PAD   50048      // 391 * 128 (also multiple of 64)
#define NUM_E   800000
#define FDIM    256
#define NREL    8
#define NSEG    (N_NODES * NREL)       // 400000 (dst,rel) segments
#define NBLK    391                    // ceil(NSEG/1024)

__device__ __forceinline__ u16 f2bf(float f) {
  uint32_t u = __float_as_uint(f);
  u += 0x7FFFu + ((u >> 16) & 1u);   // RNE
  return (u16)(u >> 16);
}
__device__ __forceinline__ float bf2f(u16 h) {
  return __uint_as_float(((uint32_t)h) << 16);
}

// async global->LDS, 16B per lane; LDS dest = wave-uniform base + lane*16
__device__ __forceinline__ void gload_lds16(const void* g, void* l) {
  __builtin_amdgcn_global_load_lds(
      (__attribute__((address_space(1))) uint32_t*)(void*)(uintptr_t)g,
      (__attribute__((address_space(3))) uint32_t*)(uintptr_t)l,
      16, 0, 0);
}

// ---- prep: feat f32 -> bf16, rows >= N_NODES zero-padded ----
__global__ __launch_bounds__(256) void feat_conv(const float* __restrict__ feat,
                                                 u16* __restrict__ fb) {
  int idx = blockIdx.x * 256 + threadIdx.x;       // one thread = 4 elems
  if (idx >= N_PAD * (FDIM / 4)) return;
  int row = idx >> 6;
  int q = (idx & 63) * 4;
  float4 v = make_float4(0.f, 0.f, 0.f, 0.f);
  if (row < N_NODES) v = *reinterpret_cast<const float4*>(feat + (size_t)row * FDIM + q);
  ushort4 h;
  h.x = f2bf(v.x); h.y = f2bf(v.y); h.z = f2bf(v.z); h.w = f2bf(v.w);
  *reinterpret_cast<ushort4*>(fb + (size_t)row * FDIM + q) = h;
}

// ---- prep: W_all[r][o][i]: r<8 = sum_b w_comp[r][b]*weight[b][i][o];
//            r==8 = loop_weight[i][o]  (all bf16, o-major = B^T layout) ----
__global__ __launch_bounds__(256) void wt_conv(const float* __restrict__ weight,
                                               const float* __restrict__ w_comp,
                                               const float* __restrict__ loop_w,
                                               u16* __restrict__ W_all) {
  int idx = blockIdx.x * 256 + threadIdx.x;
  if (idx < NREL * 65536) {
    int r = idx >> 16, rem = idx & 65535;
    int o = rem >> 8, i = rem & 255;
    float s = 0.f;
#pragma unroll
    for (int b = 0; b < 4; ++b)
      s += w_comp[r * 4 + b] * weight[b * 65536 + i * 256 + o];
    W_all[idx] = f2bf(s);
  } else if (idx < (NREL + 1) * 65536) {
    int j = idx - NREL * 65536;
    int o = j >> 8, i = j & 255;
    W_all[idx] = f2bf(loop_w[i * 256 + o]);
  }
}

// ---- CSR build over key = dst*8 + etype ----
__global__ __launch_bounds__(256) void hist_k(const int* __restrict__ dst,
                                              const int* __restrict__ et,
                                              int* __restrict__ cnt) {
  int e = blockIdx.x * 256 + threadIdx.x;
  if (e < NUM_E) atomicAdd(&cnt[dst[e] * NREL + et[e]], 1);
}

// block-level scan (1024/block): rowstart[i] = in-block exclusive prefix
__global__ __launch_bounds__(1024) void scan1(const int* __restrict__ cnt,
                                              int* __restrict__ rowstart,
                                              int* __restrict__ blocksum) {
  __shared__ int wtot[16], woff[16];
  const int tid = threadIdx.x, lane = tid & 63, w = tid >> 6;
  const int i = blockIdx.x * 1024 + tid;
  const int v = (i < NSEG) ? cnt[i] : 0;
  int inc = v;
#pragma unroll
  for (int off = 1; off < 64; off <<= 1) {
    int t = __shfl_up(inc, off);
    if (lane >= off) inc += t;
  }
  if (lane == 63) wtot[w] = inc;
  __syncthreads();
  if (w == 0) {
    int tv = (lane < 16) ? wtot[lane] : 0;
    int tinc = tv;
#pragma unroll
    for (int off = 1; off < 16; off <<= 1) {
      int t = __shfl_up(tinc, off);
      if (lane >= off) tinc += t;
    }
    if (lane < 16) woff[lane] = tinc - tv;
    if (lane == 15) blocksum[blockIdx.x] = tinc;
  }
  __syncthreads();
  if (i < NSEG) rowstart[i] = inc - v + woff[w];
}

// exclusive scan of the 391 block sums (single block)
__global__ __launch_bounds__(512) void scan2(int* __restrict__ blocksum) {
  __shared__ int s[512];
  const int tid = threadIdx.x;
  const int v = (tid < NBLK) ? blocksum[tid] : 0;
  s[tid] = v;
#pragma unroll
  for (int off = 1; off < 512; off <<= 1) {
    __syncthreads();
    int t = (tid >= off) ? s[tid - off] : 0;
    __syncthreads();
    s[tid] += t;
  }
  if (tid < NBLK) blocksum[tid] = s[tid] - v;
}

// add block offsets in place; init cursor; terminator
__global__ __launch_bounds__(1024) void scan3(int* __restrict__ rowstart,
                                              const int* __restrict__ blockoff,
                                              int* __restrict__ cursor) {
  const int i = blockIdx.x * 1024 + threadIdx.x;
  if (i < NSEG) {
    const int v = rowstart[i] + blockoff[i >> 10];
    rowstart[i] = v;
    cursor[i] = v;
  }
  if (i == NSEG) rowstart[NSEG] = NUM_E;
}

// bucket edges into CSR order: store src and norm
__global__ __launch_bounds__(256) void bucket_k(const int* __restrict__ src,
                                                const int* __restrict__ dst,
                                                const int* __restrict__ et,
                                                const float* __restrict__ norm,
                                                int* __restrict__ cursor,
                                                int* __restrict__ keys,
                                                float* __restrict__ norms) {
  int e = blockIdx.x * 256 + threadIdx.x;
  if (e >= NUM_E) return;
  const int pos = atomicAdd(&cursor[dst[e] * NREL + et[e]], 1);
  keys[pos]  = src[e];
  norms[pos] = norm[e];
}

// ---- aggregate features per (dst, rel): T[dst][r][:] = sum norm*feat[src]
//      2 waves per node: wave handles 4 relations (halves serial edge chain) ----
__global__ __launch_bounds__(256) void agg_T(const u16* __restrict__ feat_bf,
                                             const int* __restrict__ rowstart,
                                             const int* __restrict__ keys,
                                             const float* __restrict__ norms,
                                             u16* __restrict__ T) {
  const int w = threadIdx.x >> 6;                 // 0..3
  const int n = blockIdx.x * 2 + (w >> 1);
  if (n >= N_NODES) return;
  const int roff = (w & 1) * 4;                   // rels roff..roff+3
  const int lane = threadIdx.x & 63;
  int rsv = 0;
  if (lane < 5) rsv = rowstart[n * NREL + roff + lane];  // [roff..roff+4]
  f32x4 acc[4] = {};
#pragma unroll
  for (int rr = 0; rr < 4; ++rr) {
    const int b = __shfl(rsv, rr), e = __shfl(rsv, rr + 1);
    for (int base = b; base < e; base += 64) {
      const int m = min(64, e - base);
      int kv = 0; float nv = 0.f;
      if (lane < m) { kv = keys[base + lane]; nv = norms[base + lane]; }
      for (int j = 0; j < m; ++j) {
        const int s = __shfl(kv, j);
        const float nm = __shfl(nv, j);
        const ushort4 h = *reinterpret_cast<const ushort4*>(
            feat_bf + (size_t)s * FDIM + lane * 4);
        acc[rr][0] += bf2f(h.x) * nm;
        acc[rr][1] += bf2f(h.y) * nm;
        acc[rr][2] += bf2f(h.z) * nm;
        acc[rr][3] += bf2f(h.w) * nm;
      }
    }
  }
#pragma unroll
  for (int rr = 0; rr < 4; ++rr) {
    ushort4 hh;
    hh.x = f2bf(acc[rr][0]);
    hh.y = f2bf(acc[rr][1]);
    hh.z = f2bf(acc[rr][2]);
    hh.w = f2bf(acc[rr][3]);
    *reinterpret_cast<ushort4*>(T + (size_t)n * (NREL * FDIM) + (roff + rr) * FDIM + lane * 4) = hh;
  }
}

// ---- fused GEMM: out[m][o] = relu( sum_{r<8} T[m][r][:]@W_r + feat[m]@lw + bias )
//      BM=64, BN=256, BK=64, K = 9*256 = 2304 (36 steps), 8 waves (2Mx4N),
//      double-buffered LDS, early-stage 2-phase pipeline (1 barrier/step) ----
__global__ __launch_bounds__(512) void fused_gemm(const u16* __restrict__ T,
                                                  const u16* __restrict__ feat_bf,
                                                  const u16* __restrict__ W_all,
                                                  const float* __restrict__ bias,
                                                  float* __restrict__ out) {
  __shared__ __align__(16) u16 As[2][64 * 64];    // 2 x 8 KB
  __shared__ __align__(16) u16 Bs[2][256 * 64];   // 2 x 32 KB  (total 80 KB)
  const int tid = threadIdx.x;
  const int lane = tid & 63;
  const int w = tid >> 6;          // 0..7
  const int wm = w >> 2, wn = w & 3;
  const int mtile = blockIdx.x;

  f32x4 acc[2][4] = {};

  // stage K-step ks into buffer buf
  auto stage = [&](int ks, int buf) {
    const int r = ks >> 2, kk = ks & 3;
    const u16* Asrc; int stride;
    if (r < 8) { Asrc = T + (size_t)mtile * 64 * 2048 + r * 256 + kk * 64; stride = 2048; }
    else       { Asrc = feat_bf + (size_t)mtile * 64 * 256 + kk * 64;      stride = 256; }
    {  // A: 64 rows x 64 cols = 8 KB = 512 threads x 16B
      const int row = tid >> 3, c8 = tid & 7;
      gload_lds16(Asrc + (size_t)row * stride + c8 * 8, &As[buf][tid * 8]);
    }
    const u16* Bsrc = W_all + (size_t)r * 65536 + kk * 64;
#pragma unroll
    for (int it = 0; it < 4; ++it) {   // B: 256 rows x 64 cols = 32 KB
      const int idx = it * 512 + tid;
      const int row = idx >> 3, c8 = idx & 7;
      gload_lds16(Bsrc + (size_t)row * 256 + c8 * 8, &Bs[buf][idx * 8]);
    }
  };

  stage(0, 0);
  __syncthreads();                       // vmcnt(0) drain + barrier
  int cur = 0;
  for (int ks = 0; ks < 36; ++ks) {
    if (ks + 1 < 36) stage(ks + 1, cur ^ 1);   // prefetch overlaps compute below
#pragma unroll
    for (int k2 = 0; k2 < 2; ++k2) {
      const int kb = k2 * 32 + (lane >> 4) * 8;
      bf16x8 a[2], b[4];
#pragma unroll
      for (int mf = 0; mf < 2; ++mf)
        a[mf] = *reinterpret_cast<const bf16x8*>(&As[cur][(wm * 32 + mf * 16 + (lane & 15)) * 64 + kb]);
#pragma unroll
      for (int nf = 0; nf < 4; ++nf)
        b[nf] = *reinterpret_cast<const bf16x8*>(&Bs[cur][(wn * 64 + nf * 16 + (lane & 15)) * 64 + kb]);
#pragma unroll
      for (int mf = 0; mf < 2; ++mf)
#pragma unroll
        for (int nf = 0; nf < 4; ++nf)
          acc[mf][nf] = __builtin_amdgcn_mfma_f32_16x16x32_bf16(b[nf], a[mf], acc[mf][nf], 0, 0, 0);
    }
    __syncthreads();                     // drains stage vmcnt + all ds_reads
    cur ^= 1;
  }

  // epilogue: out = relu(acc + bias), o lane-sequential -> float4 stores
#pragma unroll
  for (int mf = 0; mf < 2; ++mf) {
    const int m = mtile * 64 + wm * 32 + mf * 16 + (lane & 15);
    if (m >= N_NODES) continue;
#pragma unroll
    for (int nf = 0; nf < 4; ++nf) {
      const int o0 = wn * 64 + nf * 16 + ((lane >> 4) << 2);
      const float4 bv = *reinterpret_cast<const float4*>(bias + o0);
      float4 v;
      v.x = fmaxf(acc[mf][nf][0] + bv.x, 0.f);
      v.y = fmaxf(acc[mf][nf][1] + bv.y, 0.f);
      v.z = fmaxf(acc[mf][nf][2] + bv.z, 0.f);
      v.w = fmaxf(acc[mf][nf][3] + bv.w, 0.f);
      *reinterpret_cast<float4*>(out + (size_t)m * 256 + o0) = v;
    }
  }
}

extern "C" void kernel_launch(void* const* d_in, const int* in_sizes, int n_in,
                              void* d_out, int out_size, void* d_ws, size_t ws_size,
                              hipStream_t stream) {
  (void)in_sizes; (void)n_in; (void)out_size; (void)ws_size;
  const float* feat   = (const float*)d_in[0];
  const float* weight = (const float*)d_in[1];
  const float* w_comp = (const float*)d_in[2];
  const float* loop_w = (const float*)d_in[3];
  const float* h_bias = (const float*)d_in[4];
  const float* norm   = (const float*)d_in[5];
  const int*   src    = (const int*)d_in[6];
  const int*   dst    = (const int*)d_in[7];
  const int*   et     = (const int*)d_in[8];
  float* out = (float*)d_out;

  char* ws = (char*)d_ws;
  u16*   feat_bf  = (u16*)(ws);                      // 25,624,576
  u16*   W_all    = (u16*)(ws + 25624576);           //  1,179,648
  u16*   T        = (u16*)(ws + 26804224);           // 205,000,704 (N_PAD*2048*2)
  int*   counts   = (int*)(ws + 231804928);          //  1,600,000
  int*   rowstart = (int*)(ws + 233404928);          //  1,600,256 (NSEG+1, padded)
  int*   cursor   = (int*)(ws + 235005184);          //  1,600,000
  int*   keys     = (int*)(ws + 236605184);          //  3,200,000
  float* norms    = (float*)(ws + 239805184);        //  3,200,000
  int*   blocksum = (int*)(ws + 243005184);          //      1,564

  // CSR build over (dst, rel)
  hipMemsetAsync(counts, 0, NSEG * sizeof(int), stream);
  hist_k<<<(NUM_E + 255) / 256, 256, 0, stream>>>(dst, et, counts);
  scan1<<<NBLK, 1024, 0, stream>>>(counts, rowstart, blocksum);
  scan2<<<1, 512, 0, stream>>>(blocksum);
  scan3<<<NBLK + 1, 1024, 0, stream>>>(rowstart, blocksum, cursor);
  bucket_k<<<(NUM_E + 255) / 256, 256, 0, stream>>>(src, dst, et, norm, cursor, keys, norms);

  // dense prep
  feat_conv<<<N_PAD / 4, 256, 0, stream>>>(feat, feat_bf);
  wt_conv<<<(NREL + 1) * 65536 / 256, 256, 0, stream>>>(weight, w_comp, loop_w, W_all);

  // aggregate feats per (dst, rel): 2 waves/node
  agg_T<<<(N_NODES + 1) / 2, 256, 0, stream>>>(feat_bf, rowstart, keys, norms, T);

  // one fused GEMM: K = 8 relations + self-loop; bias + relu fused
  fused_gemm<<<N_PAD / 64, 512, 0, stream>>>(T, feat_bf, W_all, h_bias, out);
}

// Round 6
// 278.917 us; speedup vs baseline: 1.2280x; 1.2280x over previous
//
#include <hip/hip_runtime.h>
#include <stdint.h>

typedef unsigned short u16;
typedef __bf16 bf16x8 __attribute__((ext_vector_type(8)));
typedef float f32x4 __attribute__((ext_vector_type(4)));

#define N_NODES 50000
#define N_PAD   50048      // 391 * 128
#define NUM_E   800000
#define FDIM    256
#define NREL    8
#define NSEG    (N_NODES * NREL)       // 400000 (dst,rel) segments
#define NBLK    391                    // ceil(NSEG/1024)
#define MTILES  196                    // ceil(N_PAD/256)

// prep kernel block ranges
#define PREP_FEAT_BLOCKS 12512         // N_PAD*64/256
#define PREP_WT_BLOCKS   2304          // 9*65536/256
#define PREP_ZERO_BLOCKS 1563          // ceil(NSEG/256)

__device__ __forceinline__ u16 f2bf(float f) {
  uint32_t u = __float_as_uint(f);
  u += 0x7FFFu + ((u >> 16) & 1u);   // RNE
  return (u16)(u >> 16);
}
__device__ __forceinline__ float bf2f(u16 h) {
  return __uint_as_float(((uint32_t)h) << 16);
}

// async global->LDS, 16B per lane; LDS dest = wave-uniform base + lane*16
__device__ __forceinline__ void gload_lds16(const void* g, void* l) {
  __builtin_amdgcn_global_load_lds(
      (__attribute__((address_space(1))) uint32_t*)(void*)(uintptr_t)g,
      (__attribute__((address_space(3))) uint32_t*)(uintptr_t)l,
      16, 0, 0);
}

// ---- fused prep: feat f32->bf16 (zero-pad), W_all build, zero counts ----
__global__ __launch_bounds__(256) void prep_k(const float* __restrict__ feat,
                                              const float* __restrict__ weight,
                                              const float* __restrict__ w_comp,
                                              const float* __restrict__ loop_w,
                                              u16* __restrict__ fb,
                                              u16* __restrict__ W_all,
                                              int* __restrict__ cnt) {
  const int b = blockIdx.x;
  const int tid = threadIdx.x;
  if (b < PREP_FEAT_BLOCKS) {
    int idx = b * 256 + tid;                      // one thread = 4 elems
    int row = idx >> 6;
    int q = (idx & 63) * 4;
    float4 v = make_float4(0.f, 0.f, 0.f, 0.f);
    if (row < N_NODES) v = *reinterpret_cast<const float4*>(feat + (size_t)row * FDIM + q);
    ushort4 h;
    h.x = f2bf(v.x); h.y = f2bf(v.y); h.z = f2bf(v.z); h.w = f2bf(v.w);
    *reinterpret_cast<ushort4*>(fb + (size_t)row * FDIM + q) = h;
  } else if (b < PREP_FEAT_BLOCKS + PREP_WT_BLOCKS) {
    int idx = (b - PREP_FEAT_BLOCKS) * 256 + tid;
    if (idx < NREL * 65536) {
      int r = idx >> 16, rem = idx & 65535;
      int o = rem >> 8, i = rem & 255;
      float s = 0.f;
#pragma unroll
      for (int bb = 0; bb < 4; ++bb)
        s += w_comp[r * 4 + bb] * weight[bb * 65536 + i * 256 + o];
      W_all[idx] = f2bf(s);                       // layout r*65536 + o*256 + i
    } else {
      int j = idx - NREL * 65536;
      int o = j >> 8, i = j & 255;
      W_all[idx] = f2bf(loop_w[i * 256 + o]);
    }
  } else {
    int i = (b - PREP_FEAT_BLOCKS - PREP_WT_BLOCKS) * 256 + tid;
    if (i < NSEG) cnt[i] = 0;
  }
}

// ---- CSR build over key = dst*8 + etype ----
__global__ __launch_bounds__(256) void hist_k(const int* __restrict__ dst,
                                              const int* __restrict__ et,
                                              int* __restrict__ cnt) {
  int e = blockIdx.x * 256 + threadIdx.x;
  if (e < NUM_E) atomicAdd(&cnt[dst[e] * NREL + et[e]], 1);
}

// block-level scan (1024/block): rowstart[i] = in-block exclusive prefix
__global__ __launch_bounds__(1024) void scan1(const int* __restrict__ cnt,
                                              int* __restrict__ rowstart,
                                              int* __restrict__ blocksum) {
  __shared__ int wtot[16], woff[16];
  const int tid = threadIdx.x, lane = tid & 63, w = tid >> 6;
  const int i = blockIdx.x * 1024 + tid;
  const int v = (i < NSEG) ? cnt[i] : 0;
  int inc = v;
#pragma unroll
  for (int off = 1; off < 64; off <<= 1) {
    int t = __shfl_up(inc, off);
    if (lane >= off) inc += t;
  }
  if (lane == 63) wtot[w] = inc;
  __syncthreads();
  if (w == 0) {
    int tv = (lane < 16) ? wtot[lane] : 0;
    int tinc = tv;
#pragma unroll
    for (int off = 1; off < 16; off <<= 1) {
      int t = __shfl_up(tinc, off);
      if (lane >= off) tinc += t;
    }
    if (lane < 16) woff[lane] = tinc - tv;
    if (lane == 15) blocksum[blockIdx.x] = tinc;
  }
  __syncthreads();
  if (i < NSEG) rowstart[i] = inc - v + woff[w];
}

// exclusive scan of the 391 block sums (single block)
__global__ __launch_bounds__(512) void scan2(int* __restrict__ blocksum) {
  __shared__ int s[512];
  const int tid = threadIdx.x;
  const int v = (tid < NBLK) ? blocksum[tid] : 0;
  s[tid] = v;
#pragma unroll
  for (int off = 1; off < 512; off <<= 1) {
    __syncthreads();
    int t = (tid >= off) ? s[tid - off] : 0;
    __syncthreads();
    s[tid] += t;
  }
  if (tid < NBLK) blocksum[tid] = s[tid] - v;
}

// add block offsets in place; init cursor; terminator
__global__ __launch_bounds__(1024) void scan3(int* __restrict__ rowstart,
                                              const int* __restrict__ blockoff,
                                              int* __restrict__ cursor) {
  const int i = blockIdx.x * 1024 + threadIdx.x;
  if (i < NSEG) {
    const int v = rowstart[i] + blockoff[i >> 10];
    rowstart[i] = v;
    cursor[i] = v;
  }
  if (i == NSEG) rowstart[NSEG] = NUM_E;
}

// bucket edges into CSR order: store src and norm
__global__ __launch_bounds__(256) void bucket_k(const int* __restrict__ src,
                                                const int* __restrict__ dst,
                                                const int* __restrict__ et,
                                                const float* __restrict__ norm,
                                                int* __restrict__ cursor,
                                                int* __restrict__ keys,
                                                float* __restrict__ norms) {
  int e = blockIdx.x * 256 + threadIdx.x;
  if (e >= NUM_E) return;
  const int pos = atomicAdd(&cursor[dst[e] * NREL + et[e]], 1);
  keys[pos]  = src[e];
  norms[pos] = norm[e];
}

// ---- aggregate features per (dst, rel): T[dst][r][:] = sum norm*feat[src]
//      one wave per node (round-4 form) ----
__global__ __launch_bounds__(256) void agg_T(const u16* __restrict__ feat_bf,
                                             const int* __restrict__ rowstart,
                                             const int* __restrict__ keys,
                                             const float* __restrict__ norms,
                                             u16* __restrict__ T) {
  const int n = blockIdx.x * 4 + (threadIdx.x >> 6);
  if (n >= N_NODES) return;
  const int lane = threadIdx.x & 63;
  int rsv = 0;
  if (lane < 9) rsv = rowstart[n * NREL + lane];
  f32x4 acc[8] = {};
#pragma unroll
  for (int r = 0; r < 8; ++r) {
    const int b = __shfl(rsv, r), e = __shfl(rsv, r + 1);
    for (int base = b; base < e; base += 64) {
      const int m = min(64, e - base);
      int kv = 0; float nv = 0.f;
      if (lane < m) { kv = keys[base + lane]; nv = norms[base + lane]; }
      for (int j = 0; j < m; ++j) {
        const int s = __shfl(kv, j);
        const float nm = __shfl(nv, j);
        const ushort4 h = *reinterpret_cast<const ushort4*>(
            feat_bf + (size_t)s * FDIM + lane * 4);
        acc[r][0] += bf2f(h.x) * nm;
        acc[r][1] += bf2f(h.y) * nm;
        acc[r][2] += bf2f(h.z) * nm;
        acc[r][3] += bf2f(h.w) * nm;
      }
    }
  }
#pragma unroll
  for (int r = 0; r < 8; ++r) {
    ushort4 hh;
    hh.x = f2bf(acc[r][0]);
    hh.y = f2bf(acc[r][1]);
    hh.z = f2bf(acc[r][2]);
    hh.w = f2bf(acc[r][3]);
    *reinterpret_cast<ushort4*>(T + (size_t)n * (NREL * FDIM) + r * FDIM + lane * 4) = hh;
  }
}

// ---- fused GEMM: out[m][o] = relu( sum_{r<8} T[m][r][:]@W_r + feat[m]@lw + bias )
//      BM=256, BN=256, BK=64, K=2304 (36 steps), 8 waves (2Mx4N), wave tile 128x64.
//      Double-buffered LDS, stage-early; BOTH-SIDES XOR swizzle (rule 21):
//      LDS elem (row, c) holds global (row, c ^ ((row&7)<<3)); reads apply same XOR.
//      196 blocks = 1 block/CU, LDS 128KB. ----
__global__ __launch_bounds__(512, 2) void fused_gemm(const u16* __restrict__ T,
                                                     const u16* __restrict__ feat_bf,
                                                     const u16* __restrict__ W_all,
                                                     const float* __restrict__ bias,
                                                     float* __restrict__ out) {
  __shared__ __align__(16) u16 As[2][256 * 64];   // 2 x 32 KB
  __shared__ __align__(16) u16 Bs[2][256 * 64];   // 2 x 32 KB
  const int tid = threadIdx.x;
  const int lane = tid & 63;
  const int w = tid >> 6;          // 0..7
  const int wm = w >> 2, wn = w & 3;
  const int mtile = blockIdx.x;

  // per-thread staging constants (source pre-swizzle)
  const int srow = tid >> 3;                      // 0..63: row within 64-row group
  const int scolx = ((tid & 7) << 3) ^ ((srow & 7) << 3);  // swizzled elem col

  f32x4 acc[8][4] = {};

  // stage K-step ks into buffer buf: A 256x64 from T/feat, B 256x64 from W_all
  auto stage = [&](int ks, int buf) {
    const int r = ks >> 2, kk4 = ks & 3;
    const int kcol = kk4 * 64 + scolx;
#pragma unroll
    for (int q = 0; q < 4; ++q) {
      const int arow = q * 64 + srow;             // 0..255 within tile
      int gr = mtile * 256 + arow;
      if (gr >= N_PAD) gr = N_PAD - 1;            // clamp (garbage rows discarded)
      const u16* asrc = (r < 8)
          ? T + (size_t)gr * 2048 + r * 256 + kcol
          : feat_bf + (size_t)gr * 256 + kcol;
      gload_lds16(asrc, &As[buf][q * 4096 + tid * 8]);
      const u16* bsrc = W_all + (size_t)r * 65536 + (size_t)arow * 256 + kcol;
      gload_lds16(bsrc, &Bs[buf][q * 4096 + tid * 8]);
    }
  };

  stage(0, 0);
  __syncthreads();
  for (int t = 0; t < 36; ++t) {
    const int cur = t & 1;
    if (t + 1 < 36) stage(t + 1, cur ^ 1);        // flight hidden under compute
#pragma unroll
    for (int kk = 0; kk < 2; ++kk) {
      const int colx = (kk * 32 + ((lane >> 4) << 3)) ^ ((lane & 7) << 3);
      bf16x8 a[8], b[4];
#pragma unroll
      for (int mf = 0; mf < 8; ++mf)
        a[mf] = *reinterpret_cast<const bf16x8*>(
            &As[cur][(wm * 128 + mf * 16 + (lane & 15)) * 64 + colx]);
#pragma unroll
      for (int nf = 0; nf < 4; ++nf)
        b[nf] = *reinterpret_cast<const bf16x8*>(
            &Bs[cur][(wn * 64 + nf * 16 + (lane & 15)) * 64 + colx]);
      __builtin_amdgcn_s_setprio(1);
#pragma unroll
      for (int mf = 0; mf < 8; ++mf)
#pragma unroll
        for (int nf = 0; nf < 4; ++nf)
          acc[mf][nf] = __builtin_amdgcn_mfma_f32_16x16x32_bf16(b[nf], a[mf], acc[mf][nf], 0, 0, 0);
      __builtin_amdgcn_s_setprio(0);
    }
    __syncthreads();                              // drains stage + read-protect
  }

  // epilogue: out = relu(acc + bias); D col(lane&15)=m, rows(reg)=o
#pragma unroll
  for (int mf = 0; mf < 8; ++mf) {
    const int m = mtile * 256 + wm * 128 + mf * 16 + (lane & 15);
    if (m >= N_NODES) continue;
#pragma unroll
    for (int nf = 0; nf < 4; ++nf) {
      const int o0 = wn * 64 + nf * 16 + ((lane >> 4) << 2);
      const float4 bv = *reinterpret_cast<const float4*>(bias + o0);
      float4 v;
      v.x = fmaxf(acc[mf][nf][0] + bv.x, 0.f);
      v.y = fmaxf(acc[mf][nf][1] + bv.y, 0.f);
      v.z = fmaxf(acc[mf][nf][2] + bv.z, 0.f);
      v.w = fmaxf(acc[mf][nf][3] + bv.w, 0.f);
      *reinterpret_cast<float4*>(out + (size_t)m * 256 + o0) = v;
    }
  }
}

extern "C" void kernel_launch(void* const* d_in, const int* in_sizes, int n_in,
                              void* d_out, int out_size, void* d_ws, size_t ws_size,
                              hipStream_t stream) {
  (void)in_sizes; (void)n_in; (void)out_size; (void)ws_size;
  const float* feat   = (const float*)d_in[0];
  const float* weight = (const float*)d_in[1];
  const float* w_comp = (const float*)d_in[2];
  const float* loop_w = (const float*)d_in[3];
  const float* h_bias = (const float*)d_in[4];
  const float* norm   = (const float*)d_in[5];
  const int*   src    = (const int*)d_in[6];
  const int*   dst    = (const int*)d_in[7];
  const int*   et     = (const int*)d_in[8];
  float* out = (float*)d_out;

  char* ws = (char*)d_ws;
  u16*   feat_bf  = (u16*)(ws);                      // 25,624,576
  u16*   W_all    = (u16*)(ws + 25624576);           //  1,179,648
  u16*   T        = (u16*)(ws + 26804224);           // 204,996,608 (N_PAD*2048*2)
  int*   counts   = (int*)(ws + 231804928);          //  1,600,000
  int*   rowstart = (int*)(ws + 233404928);          //  1,600,256 (NSEG+1, padded)
  int*   cursor   = (int*)(ws + 235005184);          //  1,600,000
  int*   keys     = (int*)(ws + 236605184);          //  3,200,000
  float* norms    = (float*)(ws + 239805184);        //  3,200,000
  int*   blocksum = (int*)(ws + 243005184);          //      1,564

  // fused prep: feat->bf16, W_all, zero counts
  prep_k<<<PREP_FEAT_BLOCKS + PREP_WT_BLOCKS + PREP_ZERO_BLOCKS, 256, 0, stream>>>(
      feat, weight, w_comp, loop_w, feat_bf, W_all, counts);

  // CSR build over (dst, rel)
  hist_k<<<(NUM_E + 255) / 256, 256, 0, stream>>>(dst, et, counts);
  scan1<<<NBLK, 1024, 0, stream>>>(counts, rowstart, blocksum);
  scan2<<<1, 512, 0, stream>>>(blocksum);
  scan3<<<NBLK + 1, 1024, 0, stream>>>(rowstart, blocksum, cursor);
  bucket_k<<<(NUM_E + 255) / 256, 256, 0, stream>>>(src, dst, et, norm, cursor, keys, norms);

  // aggregate feats per (dst, rel): 1 wave/node
  agg_T<<<(N_NODES + 3) / 4, 256, 0, stream>>>(feat_bf, rowstart, keys, norms, T);

  // one fused GEMM: K = 8 relations + self-loop; bias + relu fused
  fused_gemm<<<MTILES, 512, 0, stream>>>(T, feat_bf, W_all, h_bias, out);
}

// Round 7
// 229.123 us; speedup vs baseline: 1.4949x; 1.2173x over previous
//
#include <hip/hip_runtime.h>
#include <stdint.h>

typedef unsigned short u16;
typedef __bf16 bf16x8 __attribute__((ext_vector_type(8)));
typedef float f32x4 __attribute__((ext_vector_type(4)));

#define N_NODES 50000
#define N_PAD   50048      // 391 * 128
#define NUM_E   800000
#define FDIM    256
#define NREL    8
#define NBASE   4
#define KBLK    5                      // 4 bases + self-loop
#define NKSTEP  20                     // KBLK * 4 (BK=64)
#define NSEG    N_NODES                // dst-only segments
#define NBLK    49                     // ceil(NSEG/1024)
#define MTILES  196                    // ceil(N_PAD/256)

// prep kernel block ranges
#define PREP_FEAT_BLOCKS 12512         // N_PAD*64/256
#define PREP_WT_BLOCKS   1280          // 5*65536/256
#define PREP_ZERO_BLOCKS 196           // ceil(NSEG/256)

__device__ __forceinline__ u16 f2bf(float f) {
  uint32_t u = __float_as_uint(f);
  u += 0x7FFFu + ((u >> 16) & 1u);   // RNE
  return (u16)(u >> 16);
}
__device__ __forceinline__ float bf2f(u16 h) {
  return __uint_as_float(((uint32_t)h) << 16);
}

// async global->LDS, 16B per lane; LDS dest = wave-uniform base + lane*16
__device__ __forceinline__ void gload_lds16(const void* g, void* l) {
  __builtin_amdgcn_global_load_lds(
      (__attribute__((address_space(1))) uint32_t*)(void*)(uintptr_t)g,
      (__attribute__((address_space(3))) uint32_t*)(uintptr_t)l,
      16, 0, 0);
}

// ---- fused prep: feat f32->bf16 (zero-pad), Wb transpose, zero counts ----
// Wb_all[b][o][i] = weight[b][i][o] (b<4);  Wb_all[4][o][i] = loop_w[i][o]
__global__ __launch_bounds__(256) void prep_k(const float* __restrict__ feat,
                                              const float* __restrict__ weight,
                                              const float* __restrict__ loop_w,
                                              u16* __restrict__ fb,
                                              u16* __restrict__ Wb_all,
                                              int* __restrict__ cnt) {
  const int b = blockIdx.x;
  const int tid = threadIdx.x;
  if (b < PREP_FEAT_BLOCKS) {
    int idx = b * 256 + tid;                      // one thread = 4 elems
    int row = idx >> 6;
    int q = (idx & 63) * 4;
    float4 v = make_float4(0.f, 0.f, 0.f, 0.f);
    if (row < N_NODES) v = *reinterpret_cast<const float4*>(feat + (size_t)row * FDIM + q);
    ushort4 h;
    h.x = f2bf(v.x); h.y = f2bf(v.y); h.z = f2bf(v.z); h.w = f2bf(v.w);
    *reinterpret_cast<ushort4*>(fb + (size_t)row * FDIM + q) = h;
  } else if (b < PREP_FEAT_BLOCKS + PREP_WT_BLOCKS) {
    int idx = (b - PREP_FEAT_BLOCKS) * 256 + tid;
    int r = idx >> 16, rem = idx & 65535;
    int o = rem >> 8, i = rem & 255;
    float s = (r < NBASE) ? weight[(size_t)r * 65536 + i * 256 + o]
                          : loop_w[i * 256 + o];
    Wb_all[idx] = f2bf(s);
  } else {
    int i = (b - PREP_FEAT_BLOCKS - PREP_WT_BLOCKS) * 256 + tid;
    if (i < NSEG) cnt[i] = 0;
  }
}

// ---- CSR build over dst ----
__global__ __launch_bounds__(256) void hist_k(const int* __restrict__ dst,
                                              int* __restrict__ cnt) {
  int e = blockIdx.x * 256 + threadIdx.x;
  if (e < NUM_E) atomicAdd(&cnt[dst[e]], 1);
}

// block-level scan (1024/block): rowstart[i] = in-block exclusive prefix
__global__ __launch_bounds__(1024) void scan1(const int* __restrict__ cnt,
                                              int* __restrict__ rowstart,
                                              int* __restrict__ blocksum) {
  __shared__ int wtot[16], woff[16];
  const int tid = threadIdx.x, lane = tid & 63, w = tid >> 6;
  const int i = blockIdx.x * 1024 + tid;
  const int v = (i < NSEG) ? cnt[i] : 0;
  int inc = v;
#pragma unroll
  for (int off = 1; off < 64; off <<= 1) {
    int t = __shfl_up(inc, off);
    if (lane >= off) inc += t;
  }
  if (lane == 63) wtot[w] = inc;
  __syncthreads();
  if (w == 0) {
    int tv = (lane < 16) ? wtot[lane] : 0;
    int tinc = tv;
#pragma unroll
    for (int off = 1; off < 16; off <<= 1) {
      int t = __shfl_up(tinc, off);
      if (lane >= off) tinc += t;
    }
    if (lane < 16) woff[lane] = tinc - tv;
    if (lane == 15) blocksum[blockIdx.x] = tinc;
  }
  __syncthreads();
  if (i < NSEG) rowstart[i] = inc - v + woff[w];
}

// exclusive scan of the block sums (single block)
__global__ __launch_bounds__(512) void scan2(int* __restrict__ blocksum) {
  __shared__ int s[512];
  const int tid = threadIdx.x;
  const int v = (tid < NBLK) ? blocksum[tid] : 0;
  s[tid] = v;
#pragma unroll
  for (int off = 1; off < 512; off <<= 1) {
    __syncthreads();
    int t = (tid >= off) ? s[tid - off] : 0;
    __syncthreads();
    s[tid] += t;
  }
  if (tid < NBLK) blocksum[tid] = s[tid] - v;
}

// add block offsets in place; init cursor; terminator
__global__ __launch_bounds__(1024) void scan3(int* __restrict__ rowstart,
                                              const int* __restrict__ blockoff,
                                              int* __restrict__ cursor) {
  const int i = blockIdx.x * 1024 + threadIdx.x;
  if (i < NSEG) {
    const int v = rowstart[i] + blockoff[i >> 10];
    rowstart[i] = v;
    cursor[i] = v;
  }
  if (i == NSEG) rowstart[NSEG] = NUM_E;
}

// bucket edges into CSR order: key = src*8 + etype, plus norm
__global__ __launch_bounds__(256) void bucket_k(const int* __restrict__ src,
                                                const int* __restrict__ dst,
                                                const int* __restrict__ et,
                                                const float* __restrict__ norm,
                                                int* __restrict__ cursor,
                                                int* __restrict__ keys,
                                                float* __restrict__ norms) {
  int e = blockIdx.x * 256 + threadIdx.x;
  if (e >= NUM_E) return;
  const int pos = atomicAdd(&cursor[dst[e]], 1);
  keys[pos]  = src[e] * NREL + et[e];
  norms[pos] = norm[e];
}

// ---- aggregate into base channels:
//      G[d][b][:] = sum_{e->d} norm_e * w_comp[et_e][b] * feat[src_e][:]
//      one wave per dst node, 1-ahead prefetch of the gather row ----
__global__ __launch_bounds__(256) void agg_G(const u16* __restrict__ feat_bf,
                                             const int* __restrict__ rowstart,
                                             const int* __restrict__ keys,
                                             const float* __restrict__ norms,
                                             const float* __restrict__ w_comp,
                                             u16* __restrict__ G) {
  __shared__ float wcs[NREL * NBASE];
  if (threadIdx.x < NREL * NBASE) wcs[threadIdx.x] = w_comp[threadIdx.x];
  __syncthreads();
  const int n = blockIdx.x * 4 + (threadIdx.x >> 6);   // grid exact: n < N_NODES
  const int lane = threadIdx.x & 63;
  const int beg = rowstart[n], end = rowstart[n + 1];

  f32x4 acc[NBASE] = {};
  for (int base = beg; base < end; base += 64) {
    const int m = min(64, end - base);
    int kv = 0; float nv = 0.f;
    if (lane < m) { kv = keys[base + lane]; nv = norms[base + lane]; }
    int key = __shfl(kv, 0);
    float nm = __shfl(nv, 0);
    ushort4 h = *reinterpret_cast<const ushort4*>(
        feat_bf + (size_t)(key >> 3) * FDIM + lane * 4);
    for (int j = 0; j < m; ++j) {
      ushort4 h2; int key2 = 0; float nm2 = 0.f;
      if (j + 1 < m) {
        key2 = __shfl(kv, j + 1);
        nm2 = __shfl(nv, j + 1);
        h2 = *reinterpret_cast<const ushort4*>(
            feat_bf + (size_t)(key2 >> 3) * FDIM + lane * 4);
      }
      const int et = key & 7;
      const float f0 = bf2f(h.x), f1 = bf2f(h.y), f2 = bf2f(h.z), f3 = bf2f(h.w);
#pragma unroll
      for (int bb = 0; bb < NBASE; ++bb) {
        const float c = nm * wcs[et * NBASE + bb];
        acc[bb][0] += f0 * c;
        acc[bb][1] += f1 * c;
        acc[bb][2] += f2 * c;
        acc[bb][3] += f3 * c;
      }
      h = h2; key = key2; nm = nm2;
    }
  }
#pragma unroll
  for (int bb = 0; bb < NBASE; ++bb) {
    ushort4 hh;
    hh.x = f2bf(acc[bb][0]);
    hh.y = f2bf(acc[bb][1]);
    hh.z = f2bf(acc[bb][2]);
    hh.w = f2bf(acc[bb][3]);
    *reinterpret_cast<ushort4*>(G + (size_t)n * (NBASE * FDIM) + bb * FDIM + lane * 4) = hh;
  }
}

// ---- fused GEMM: out[m][o] = relu( sum_{b<4} G[m][b][:]@V_b + feat[m]@lw + bias )
//      BM=256, BN=256, BK=64, K=1280 (20 steps), 8 waves (2Mx4N), wave tile 128x64.
//      Double-buffered LDS, stage-early, both-sides XOR swizzle (verified r6: 0 conflicts). ----
__global__ __launch_bounds__(512, 2) void fused_gemm(const u16* __restrict__ G,
                                                     const u16* __restrict__ feat_bf,
                                                     const u16* __restrict__ Wb_all,
                                                     const float* __restrict__ bias,
                                                     float* __restrict__ out) {
  __shared__ __align__(16) u16 As[2][256 * 64];   // 2 x 32 KB
  __shared__ __align__(16) u16 Bs[2][256 * 64];   // 2 x 32 KB
  const int tid = threadIdx.x;
  const int lane = tid & 63;
  const int w = tid >> 6;          // 0..7
  const int wm = w >> 2, wn = w & 3;
  const int mtile = blockIdx.x;

  // per-thread staging constants (source pre-swizzle)
  const int srow = tid >> 3;                      // 0..63: row within 64-row group
  const int scolx = ((tid & 7) << 3) ^ ((srow & 7) << 3);  // swizzled elem col

  f32x4 acc[8][4] = {};

  // stage K-step ks into buffer buf: A 256x64 from G/feat, B 256x64 from Wb_all
  auto stage = [&](int ks, int buf) {
    const int r = ks >> 2, kk4 = ks & 3;
    const int kcol = kk4 * 64 + scolx;
#pragma unroll
    for (int q = 0; q < 4; ++q) {
      const int arow = q * 64 + srow;             // 0..255 within tile
      int gr = mtile * 256 + arow;
      if (gr >= N_PAD) gr = N_PAD - 1;            // clamp (garbage rows discarded)
      const u16* asrc = (r < NBASE)
          ? G + (size_t)gr * 1024 + r * 256 + kcol
          : feat_bf + (size_t)gr * 256 + kcol;
      gload_lds16(asrc, &As[buf][q * 4096 + tid * 8]);
      const u16* bsrc = Wb_all + (size_t)r * 65536 + (size_t)arow * 256 + kcol;
      gload_lds16(bsrc, &Bs[buf][q * 4096 + tid * 8]);
    }
  };

  stage(0, 0);
  __syncthreads();
  for (int t = 0; t < NKSTEP; ++t) {
    const int cur = t & 1;
    if (t + 1 < NKSTEP) stage(t + 1, cur ^ 1);    // flight hidden under compute
#pragma unroll
    for (int kk = 0; kk < 2; ++kk) {
      const int colx = (kk * 32 + ((lane >> 4) << 3)) ^ ((lane & 7) << 3);
      bf16x8 a[8], b[4];
#pragma unroll
      for (int mf = 0; mf < 8; ++mf)
        a[mf] = *reinterpret_cast<const bf16x8*>(
            &As[cur][(wm * 128 + mf * 16 + (lane & 15)) * 64 + colx]);
#pragma unroll
      for (int nf = 0; nf < 4; ++nf)
        b[nf] = *reinterpret_cast<const bf16x8*>(
            &Bs[cur][(wn * 64 + nf * 16 + (lane & 15)) * 64 + colx]);
      __builtin_amdgcn_s_setprio(1);
#pragma unroll
      for (int mf = 0; mf < 8; ++mf)
#pragma unroll
        for (int nf = 0; nf < 4; ++nf)
          acc[mf][nf] = __builtin_amdgcn_mfma_f32_16x16x32_bf16(b[nf], a[mf], acc[mf][nf], 0, 0, 0);
      __builtin_amdgcn_s_setprio(0);
    }
    __syncthreads();                              // drains stage + read-protect
  }

  // epilogue: out = relu(acc + bias); D col(lane&15)=m, o lane-sequential
#pragma unroll
  for (int mf = 0; mf < 8; ++mf) {
    const int m = mtile * 256 + wm * 128 + mf * 16 + (lane & 15);
    if (m >= N_NODES) continue;
#pragma unroll
    for (int nf = 0; nf < 4; ++nf) {
      const int o0 = wn * 64 + nf * 16 + ((lane >> 4) << 2);
      const float4 bv = *reinterpret_cast<const float4*>(bias + o0);
      float4 v;
      v.x = fmaxf(acc[mf][nf][0] + bv.x, 0.f);
      v.y = fmaxf(acc[mf][nf][1] + bv.y, 0.f);
      v.z = fmaxf(acc[mf][nf][2] + bv.z, 0.f);
      v.w = fmaxf(acc[mf][nf][3] + bv.w, 0.f);
      *reinterpret_cast<float4*>(out + (size_t)m * 256 + o0) = v;
    }
  }
}

extern "C" void kernel_launch(void* const* d_in, const int* in_sizes, int n_in,
                              void* d_out, int out_size, void* d_ws, size_t ws_size,
                              hipStream_t stream) {
  (void)in_sizes; (void)n_in; (void)out_size; (void)ws_size;
  const float* feat   = (const float*)d_in[0];
  const float* weight = (const float*)d_in[1];
  const float* w_comp = (const float*)d_in[2];
  const float* loop_w = (const float*)d_in[3];
  const float* h_bias = (const float*)d_in[4];
  const float* norm   = (const float*)d_in[5];
  const int*   src    = (const int*)d_in[6];
  const int*   dst    = (const int*)d_in[7];
  const int*   et     = (const int*)d_in[8];
  float* out = (float*)d_out;

  char* ws = (char*)d_ws;
  u16*   feat_bf  = (u16*)(ws);                      // 25,624,576
  u16*   Wb_all   = (u16*)(ws + 25624576);           //    655,360
  u16*   G        = (u16*)(ws + 26279936);           // 102,498,304 (N_PAD*1024*2)
  int*   counts   = (int*)(ws + 128778240);          //    200,192
  int*   rowstart = (int*)(ws + 128978432);          //    200,448 (NSEG+1, padded)
  int*   cursor   = (int*)(ws + 129178880);          //    200,192
  int*   keys     = (int*)(ws + 129379072);          //  3,200,000
  float* norms    = (float*)(ws + 132579072);        //  3,200,000
  int*   blocksum = (int*)(ws + 135779072);          //        256

  // fused prep: feat->bf16, Wb transpose, zero counts
  prep_k<<<PREP_FEAT_BLOCKS + PREP_WT_BLOCKS + PREP_ZERO_BLOCKS, 256, 0, stream>>>(
      feat, weight, loop_w, feat_bf, Wb_all, counts);

  // CSR build over dst
  hist_k<<<(NUM_E + 255) / 256, 256, 0, stream>>>(dst, counts);
  scan1<<<NBLK, 1024, 0, stream>>>(counts, rowstart, blocksum);
  scan2<<<1, 512, 0, stream>>>(blocksum);
  scan3<<<NBLK + 1, 1024, 0, stream>>>(rowstart, blocksum, cursor);
  bucket_k<<<(NUM_E + 255) / 256, 256, 0, stream>>>(src, dst, et, norm, cursor, keys, norms);

  // aggregate into 4 base channels (1 wave/node; grid exact)
  agg_G<<<N_NODES / 4, 256, 0, stream>>>(feat_bf, rowstart, keys, norms, w_comp, G);

  // one fused GEMM: K = 4 bases + self-loop; bias + relu fused
  fused_gemm<<<MTILES, 512, 0, stream>>>(G, feat_bf, Wb_all, h_bias, out);
}